// Round 5
// baseline (453.394 us; speedup 1.0000x reference)
//
#include <hip/hip_runtime.h>
#include <cstddef>
#include <cstdint>

#define Bc 4
#define Nc 1024
#define Cc 768
#define Hc 12
#define Dc 64
#define BHc 48
#define QKV_ELEMS ((size_t)Bc * Nc * Cc)   // 3145728

typedef __attribute__((ext_vector_type(4))) unsigned int u32x4;
typedef __attribute__((ext_vector_type(8))) short s16x8;
typedef __attribute__((ext_vector_type(4))) float fx4;
typedef __attribute__((ext_vector_type(2))) float fx2;

union Frag { u32x4 u; s16x8 s; unsigned short h[8]; };

__device__ inline unsigned short f2bf(float x) {
    union { float f; uint32_t u; } c; c.f = x;
    return (unsigned short)((c.u + 0x7FFFu + ((c.u >> 16) & 1u)) >> 16);
}
__device__ inline float bf2f(unsigned short b) {
    union { uint32_t u; float f; } c; c.u = ((uint32_t)b) << 16;
    return c.f;
}
__device__ inline void split8(const float* v, u32x4& hi, u32x4& lo) {
    Frag fh, fl;
    #pragma unroll
    for (int e = 0; e < 8; ++e) {
        const unsigned short hb = f2bf(v[e]);
        fh.h[e] = hb;
        fl.h[e] = f2bf(v[e] - bf2f(hb));
    }
    hi = fh.u; lo = fl.u;
}

// ---------------------------------------------------------------------------
// prep_w: Wt_hi/lo[mat][n][k] = split(W[k][n])
// ---------------------------------------------------------------------------
__global__ __launch_bounds__(256) void prep_w_kernel(
    const float* __restrict__ Wq, const float* __restrict__ Wk,
    const float* __restrict__ Wv, const float* __restrict__ Wo,
    unsigned short* __restrict__ Thi, unsigned short* __restrict__ Tlo)
{
    __shared__ float scr[64 * 65];
    const int mat = blockIdx.z;
    const float* W = (mat == 0) ? Wq : (mat == 1) ? Wk : (mat == 2) ? Wv : Wo;
    const int k0 = blockIdx.y * 64, n0 = blockIdx.x * 64;
    const int tid = threadIdx.x;

    #pragma unroll
    for (int it = 0; it < 4; ++it) {
        const int lin = tid + it * 256;
        const int r = lin >> 4, c4 = (lin & 15) << 2;
        const fx4 v = *(const fx4*)&W[(size_t)(k0 + r) * 768 + n0 + c4];
        scr[r * 65 + c4 + 0] = v[0]; scr[r * 65 + c4 + 1] = v[1];
        scr[r * 65 + c4 + 2] = v[2]; scr[r * 65 + c4 + 3] = v[3];
    }
    __syncthreads();
    unsigned short* th = Thi + (size_t)mat * 768 * 768;
    unsigned short* tl = Tlo + (size_t)mat * 768 * 768;
    #pragma unroll
    for (int it = 0; it < 16; ++it) {
        const int lin = tid + it * 256;
        const int n = lin >> 6, kq = lin & 63;
        const float val = scr[kq * 65 + n];
        const size_t o = (size_t)(n0 + n) * 768 + k0 + kq;
        const unsigned short hb = f2bf(val);
        th[o] = hb;
        tl[o] = f2bf(val - bf2f(hb));
    }
}

// ---------------------------------------------------------------------------
// prep_tables: PL (alpha,beta) per (segment, h) + 2048-bin u8 idx LUT.
// idx(dist) = #{t: dist > kn[t]}; LUT uses bin midpoint (continuity bounds err)
// ---------------------------------------------------------------------------
__global__ __launch_bounds__(256) void prep_tables_kernel(
    const float* __restrict__ Wd1, const float* __restrict__ bd1,
    const float* __restrict__ Wd2, const float* __restrict__ bd2,
    float* __restrict__ abPack, unsigned char* __restrict__ lut)
{
    __shared__ float w1s[16], b1s[16], kn[16];
    __shared__ int rank[16];
    const int tid = threadIdx.x;
    if (tid < 16) {
        const float w1 = Wd1[tid], b1 = bd1[tid];
        w1s[tid] = w1; b1s[tid] = b1;
        kn[tid] = (w1 != 0.0f) ? (-b1 / w1) : INFINITY;
    }
    __syncthreads();
    if (tid < 16) {
        int rk = 0;
        for (int u = 0; u < 16; ++u) {
            const float ku = kn[u], km = kn[tid];
            if (ku < km || (ku == km && u < tid)) ++rk;
        }
        rank[tid] = rk;
    }
    __syncthreads();
    if (tid < 17 * 12) {
        const int s = tid / 12, h = tid % 12;
        float a = 0.0f, be = bd2[h];
        for (int u = 0; u < 16; ++u) {
            const float w1 = w1s[u], b1 = b1s[u];
            bool act;
            if (w1 > 0.0f)      act = (rank[u] < s);
            else if (w1 < 0.0f) act = (rank[u] >= s);
            else                act = (b1 > 0.0f);
            if (act) {
                const float w2 = Wd2[u * 12 + h];
                a  += w2 * w1;
                be += w2 * b1;
            }
        }
        abPack[tid * 2 + 0] = a;
        abPack[tid * 2 + 1] = be;
    }
    for (int b = tid; b < 2048; b += 256) {
        const float rep = (b + 0.5f) * (1.41422f / 2048.0f);
        int cnt = 0;
        for (int t = 0; t < 16; ++t) cnt += (rep > kn[t]) ? 1 : 0;
        lut[b] = (unsigned char)cnt;
    }
}

// ---------------------------------------------------------------------------
// split_x: x fp32 -> xhi/xlo bf16 row-major
// ---------------------------------------------------------------------------
__global__ __launch_bounds__(256) void split_x_kernel(
    const float* __restrict__ x, unsigned short* __restrict__ xhi,
    unsigned short* __restrict__ xlo)
{
    const size_t t = (size_t)blockIdx.x * 256 + threadIdx.x;
    float vv[8];
    const fx4 a = *(const fx4*)&x[t * 8];
    const fx4 b = *(const fx4*)&x[t * 8 + 4];
    vv[0]=a[0]; vv[1]=a[1]; vv[2]=a[2]; vv[3]=a[3];
    vv[4]=b[0]; vv[5]=b[1]; vv[6]=b[2]; vv[7]=b[3];
    u32x4 hi, lo; split8(vv, hi, lo);
    *(u32x4*)&xhi[t * 8] = hi;
    *(u32x4*)&xlo[t * 8] = lo;
}

// ---------------------------------------------------------------------------
// gemm_mfma: out = A[4096x768] @ W[768x768] + bias, bf16x3 MFMA.
// OMODE 0: hi/lo head layout [bh][n][d]; OMODE 1: hi/lo vT [bh][d][n];
// OMODE 2: fp32 row-major.
// ---------------------------------------------------------------------------
struct SmemG { u32x4 ah[512]; u32x4 al[512]; u32x4 bh[512]; u32x4 bl[512]; };
struct SmemT { float scr[64 * 68]; };
union SmemU { SmemG g; SmemT t; };

template<int OMODE>
__global__ __launch_bounds__(256) void gemm_mfma_kernel(
    const unsigned short* __restrict__ Ahi, const unsigned short* __restrict__ Alo,
    const unsigned short* __restrict__ Bhi, const unsigned short* __restrict__ Blo,
    const float* __restrict__ bias,
    float* __restrict__ outF,
    unsigned short* __restrict__ Ohi, unsigned short* __restrict__ Olo)
{
    __shared__ SmemU sm;
    const int tid = threadIdx.x;
    const int w = tid >> 6, L = tid & 63;
    const int Lr = L & 15, Lg = L >> 4;
    const int m0 = blockIdx.y * 64, n0 = blockIdx.x * 64;

    fx4 acc[2][2] = {};

    for (int kk = 0; kk < 768; kk += 64) {
        #pragma unroll
        for (int it = 0; it < 2; ++it) {
            const int slot = tid + it * 256;
            const int s = slot >> 6, l = slot & 63;
            const int row = m0 + ((s >> 1) << 4) + (l & 15);
            const int kb = kk + ((s & 1) << 5) + ((l >> 4) << 3);
            sm.g.ah[slot] = *(const u32x4*)&Ahi[(size_t)row * 768 + kb];
            sm.g.al[slot] = *(const u32x4*)&Alo[(size_t)row * 768 + kb];
            const int col = n0 + ((s >> 1) << 4) + (l & 15);
            sm.g.bh[slot] = *(const u32x4*)&Bhi[(size_t)col * 768 + kb];
            sm.g.bl[slot] = *(const u32x4*)&Blo[(size_t)col * 768 + kb];
        }
        __syncthreads();
        #pragma unroll
        for (int kc = 0; kc < 2; ++kc) {
            Frag ah[2], al[2], bh[2], bl[2];
            #pragma unroll
            for (int mm = 0; mm < 2; ++mm) {
                const int rg = (w >> 1) * 2 + mm;
                ah[mm].u = sm.g.ah[(rg * 2 + kc) * 64 + L];
                al[mm].u = sm.g.al[(rg * 2 + kc) * 64 + L];
            }
            #pragma unroll
            for (int nn = 0; nn < 2; ++nn) {
                const int cg = (w & 1) * 2 + nn;
                bh[nn].u = sm.g.bh[(cg * 2 + kc) * 64 + L];
                bl[nn].u = sm.g.bl[(cg * 2 + kc) * 64 + L];
            }
            #pragma unroll
            for (int mm = 0; mm < 2; ++mm)
                #pragma unroll
                for (int nn = 0; nn < 2; ++nn) {
                    acc[mm][nn] = __builtin_amdgcn_mfma_f32_16x16x32_bf16(ah[mm].s, bh[nn].s, acc[mm][nn], 0, 0, 0);
                    acc[mm][nn] = __builtin_amdgcn_mfma_f32_16x16x32_bf16(ah[mm].s, bl[nn].s, acc[mm][nn], 0, 0, 0);
                    acc[mm][nn] = __builtin_amdgcn_mfma_f32_16x16x32_bf16(al[mm].s, bh[nn].s, acc[mm][nn], 0, 0, 0);
                }
        }
        __syncthreads();
    }

    #pragma unroll
    for (int mm = 0; mm < 2; ++mm) {
        const int rl = (w >> 1) * 32 + mm * 16 + Lg * 4;
        #pragma unroll
        for (int nn = 0; nn < 2; ++nn) {
            const int cl = (w & 1) * 32 + nn * 16 + Lr;
            const float bs = bias[n0 + cl];
            #pragma unroll
            for (int r = 0; r < 4; ++r)
                sm.t.scr[(rl + r) * 68 + cl] = acc[mm][nn][r] + bs;
        }
    }
    __syncthreads();

    if (OMODE == 0) {
        const int h = n0 >> 6;
        #pragma unroll
        for (int it = 0; it < 2; ++it) {
            const int t = tid + it * 256;
            const int r = t >> 3, d0 = (t & 7) << 3;
            float vv[8];
            #pragma unroll
            for (int e = 0; e < 8; ++e) vv[e] = sm.t.scr[r * 68 + d0 + e];
            u32x4 hi, lo; split8(vv, hi, lo);
            const int rg = m0 + r, b = rg >> 10, nloc = rg & 1023;
            const size_t o = (((size_t)(b * Hc + h) * Nc + nloc) << 6) + d0;
            *(u32x4*)&Ohi[o] = hi;
            *(u32x4*)&Olo[o] = lo;
        }
    } else if (OMODE == 1) {
        const int b = m0 >> 10, h = n0 >> 6, nbase = m0 & 1023;
        #pragma unroll
        for (int it = 0; it < 2; ++it) {
            const int t = tid + it * 256;
            const int dd = t >> 3, j0 = (t & 7) << 3;
            float vv[8];
            #pragma unroll
            for (int e = 0; e < 8; ++e) vv[e] = sm.t.scr[(j0 + e) * 68 + dd];
            u32x4 hi, lo; split8(vv, hi, lo);
            const size_t o = (size_t)((b * Hc + h) * Dc + dd) * Nc + nbase + j0;
            *(u32x4*)&Ohi[o] = hi;
            *(u32x4*)&Olo[o] = lo;
        }
    } else {
        #pragma unroll
        for (int it = 0; it < 4; ++it) {
            const int lin = tid + it * 256;
            const int r = lin >> 4, c4 = (lin & 15) << 2;
            const fx4 v = *(const fx4*)&sm.t.scr[r * 68 + c4];
            *(fx4*)&outF[(size_t)(m0 + r) * 768 + n0 + c4] = v;
        }
    }
}

// ---------------------------------------------------------------------------
// scores: per (i-tile 64, j-half, bh). K frags direct from global (L1/L2).
// Writes e = exp(s - m_tile) into attn; (m_tile, l_tile) per (row, jt) -> ml.
// No barriers in the main loop.
// ---------------------------------------------------------------------------
__global__ __launch_bounds__(256) void scores_kernel(
    const unsigned short* __restrict__ qhi, const unsigned short* __restrict__ qlo,
    const unsigned short* __restrict__ khi, const unsigned short* __restrict__ klo,
    const float* __restrict__ coords,
    const float* __restrict__ abPack, const unsigned char* __restrict__ lutg,
    float* __restrict__ attn, float* __restrict__ mlf)
{
    __shared__ fx2 abt[17];
    __shared__ unsigned char luts[2048];
    __shared__ fx2 cjs[512];

    const int tid = threadIdx.x;
    const int w = tid >> 6, L = tid & 63;
    const int Lr = L & 15, Lg = L >> 4;
    const int bh = blockIdx.z, b = bh / Hc, h = bh % Hc;
    const int i0 = blockIdx.x * 64, half = blockIdx.y;
    const int i = i0 + w * 16 + Lr;
    const int Lg4 = Lg * 4;

    if (tid < 17) abt[tid] = ((const fx2*)abPack)[tid * Hc + h];
    #pragma unroll
    for (int t = tid; t < 512; t += 256) {
        ((uint32_t*)luts)[t] = ((const uint32_t*)lutg)[t];
        cjs[t] = *(const fx2*)&coords[((size_t)b * Nc + half * 512 + t) * 2];
    }

    Frag qh[2], ql[2];
    #pragma unroll
    for (int kc = 0; kc < 2; ++kc) {
        const size_t o = ((size_t)bh * Nc + i) * 64 + kc * 32 + Lg * 8;
        qh[kc].u = *(const u32x4*)&qhi[o];
        ql[kc].u = *(const u32x4*)&qlo[o];
    }
    const fx2 ci = *(const fx2*)&coords[((size_t)b * Nc + i) * 2];
    __syncthreads();

    const size_t rowbase = ((size_t)bh * Nc + i) * Nc + half * 512;
    const size_t mlbase = ((size_t)bh * Nc + i) * 16 + half * 8;

    for (int jt = 0; jt < 8; ++jt) {
        const int jbase = half * 512 + jt * 64;

        fx4 acc[4] = {};
        #pragma unroll
        for (int kc = 0; kc < 2; ++kc) {
            Frag kh[4], kl[4];
            #pragma unroll
            for (int cg = 0; cg < 4; ++cg) {
                const size_t o = ((size_t)bh * Nc + jbase + cg * 16 + Lr) * 64 + kc * 32 + Lg * 8;
                kh[cg].u = *(const u32x4*)&khi[o];
                kl[cg].u = *(const u32x4*)&klo[o];
            }
            #pragma unroll
            for (int cg = 0; cg < 4; ++cg) {
                acc[cg] = __builtin_amdgcn_mfma_f32_16x16x32_bf16(kh[cg].s, qh[kc].s, acc[cg], 0, 0, 0);
                acc[cg] = __builtin_amdgcn_mfma_f32_16x16x32_bf16(kl[cg].s, qh[kc].s, acc[cg], 0, 0, 0);
                acc[cg] = __builtin_amdgcn_mfma_f32_16x16x32_bf16(kh[cg].s, ql[kc].s, acc[cg], 0, 0, 0);
            }
        }

        float sv[16];
        #pragma unroll
        for (int cg = 0; cg < 4; ++cg) {
            #pragma unroll
            for (int r = 0; r < 4; ++r) {
                const fx2 cj = cjs[jt * 64 + cg * 16 + Lg4 + r];
                const float dx = ci[0] - cj[0], dy = ci[1] - cj[1];
                const float dist = sqrtf(fmaf(dx, dx, fmaf(dy, dy, 1e-6f)));
                int bin = (int)(dist * (2048.0f / 1.41422f));
                bin = (bin > 2047) ? 2047 : bin;
                const fx2 ab = abt[luts[bin]];
                sv[cg * 4 + r] = fmaf(acc[cg][r], 0.125f, fmaf(ab[0], dist, ab[1]));
            }
        }

        float tm = sv[0];
        #pragma unroll
        for (int e = 1; e < 16; ++e) tm = fmaxf(tm, sv[e]);
        tm = fmaxf(tm, __shfl_xor(tm, 16));
        tm = fmaxf(tm, __shfl_xor(tm, 32));

        float ts = 0.f;
        #pragma unroll
        for (int e = 0; e < 16; ++e) { sv[e] = __expf(sv[e] - tm); ts += sv[e]; }
        #pragma unroll
        for (int cg = 0; cg < 4; ++cg) {
            fx4 st;
            st[0] = sv[cg*4+0]; st[1] = sv[cg*4+1]; st[2] = sv[cg*4+2]; st[3] = sv[cg*4+3];
            *(fx4*)&attn[rowbase + jt * 64 + cg * 16 + Lg4] = st;
        }
        ts += __shfl_xor(ts, 16);
        ts += __shfl_xor(ts, 32);
        if (Lg == 0) {
            *(fx2*)&mlf[(mlbase + jt) * 2] = fx2{tm, ts};
        }
    }
}

// ---------------------------------------------------------------------------
// pv: p = e * f  (f = exp(m_t - m_row)/l_row per (row, jt)), write p to attn
// in place, heads = p @ V via bf16x3, V frags direct from global.
// Block: i-tile 32, 4 waves = (row-half wr) x (j-half wc); LDS combine.
// ---------------------------------------------------------------------------
__global__ __launch_bounds__(256) void pv_kernel(
    float* __restrict__ attn,
    const unsigned short* __restrict__ vThi, const unsigned short* __restrict__ vTlo,
    const float* __restrict__ mlf,
    unsigned short* __restrict__ Hphi, unsigned short* __restrict__ Hplo)
{
    __shared__ float accs[32 * 64];
    const int tid = threadIdx.x;
    const int w = tid >> 6, L = tid & 63;
    const int Lr = L & 15, Lg = L >> 4;
    const int wr = w >> 1, wc = w & 1;
    const int bh = blockIdx.y, b = bh / Hc, h = bh % Hc;
    const int i0 = blockIdx.x * 32;
    const int row = i0 + wr * 16 + Lr;

    const float* mlr = &mlf[((size_t)bh * Nc + row) * 32];
    float mt[16], lt[16];
    #pragma unroll
    for (int t = 0; t < 8; ++t) {
        const fx4 v = *(const fx4*)&mlr[t * 4];
        mt[t*2+0] = v[0]; lt[t*2+0] = v[1];
        mt[t*2+1] = v[2]; lt[t*2+1] = v[3];
    }
    float m_row = mt[0];
    #pragma unroll
    for (int t = 1; t < 16; ++t) m_row = fmaxf(m_row, mt[t]);
    float l_row = 0.f;
    #pragma unroll
    for (int t = 0; t < 16; ++t) l_row = fmaf(lt[t], __expf(mt[t] - m_row), l_row);
    const float il = 1.0f / l_row;

    fx4 acc[4] = {};
    const size_t arow = ((size_t)bh * Nc + row) * Nc;

    for (int jt = 0; jt < 8; ++jt) {
        const int jbase = wc * 512 + jt * 64;
        const float f = __expf(mlr[(wc * 8 + jt) * 2] - m_row) * il;
        #pragma unroll
        for (int kc = 0; kc < 2; ++kc) {
            float* ap = &attn[arow + jbase + kc * 32 + Lg * 8];
            const fx4 s0 = *(const fx4*)ap;
            const fx4 s1 = *(const fx4*)(ap + 4);
            float p[8];
            p[0]=s0[0]*f; p[1]=s0[1]*f; p[2]=s0[2]*f; p[3]=s0[3]*f;
            p[4]=s1[0]*f; p[5]=s1[1]*f; p[6]=s1[2]*f; p[7]=s1[3]*f;
            fx4 w0, w1;
            w0[0]=p[0]; w0[1]=p[1]; w0[2]=p[2]; w0[3]=p[3];
            w1[0]=p[4]; w1[1]=p[5]; w1[2]=p[6]; w1[3]=p[7];
            *(fx4*)ap = w0;
            *(fx4*)(ap + 4) = w1;
            u32x4 phiu, plou; split8(p, phiu, plou);
            Frag ph, pl; ph.u = phiu; pl.u = plou;

            Frag vh[4], vl[4];
            #pragma unroll
            for (int dg = 0; dg < 4; ++dg) {
                const size_t o = ((size_t)bh * Dc + dg * 16 + Lr) * Nc + jbase + kc * 32 + Lg * 8;
                vh[dg].u = *(const u32x4*)&vThi[o];
                vl[dg].u = *(const u32x4*)&vTlo[o];
            }
            #pragma unroll
            for (int dg = 0; dg < 4; ++dg) {
                acc[dg] = __builtin_amdgcn_mfma_f32_16x16x32_bf16(ph.s, vh[dg].s, acc[dg], 0, 0, 0);
                acc[dg] = __builtin_amdgcn_mfma_f32_16x16x32_bf16(ph.s, vl[dg].s, acc[dg], 0, 0, 0);
                acc[dg] = __builtin_amdgcn_mfma_f32_16x16x32_bf16(pl.s, vh[dg].s, acc[dg], 0, 0, 0);
            }
        }
    }

    // combine halves in LDS, then vectorized bf16 hi/lo store
    if (wc == 0) {
        #pragma unroll
        for (int dg = 0; dg < 4; ++dg)
            #pragma unroll
            for (int r = 0; r < 4; ++r)
                accs[(wr * 16 + Lg * 4 + r) * 64 + dg * 16 + Lr] = acc[dg][r];
    }
    __syncthreads();
    if (wc == 1) {
        #pragma unroll
        for (int dg = 0; dg < 4; ++dg)
            #pragma unroll
            for (int r = 0; r < 4; ++r)
                accs[(wr * 16 + Lg * 4 + r) * 64 + dg * 16 + Lr] += acc[dg][r];
    }
    __syncthreads();

    const int r2 = tid >> 3, d0 = (tid & 7) << 3;
    float vv[8];
    #pragma unroll
    for (int e = 0; e < 8; ++e) vv[e] = accs[r2 * 64 + d0 + e];
    u32x4 hi, lo; split8(vv, hi, lo);
    const size_t o = ((size_t)b * Nc + i0 + r2) * Cc + h * Dc + d0;
    *(u32x4*)&Hphi[o] = hi;
    *(u32x4*)&Hplo[o] = lo;
}

// ---------------------------------------------------------------------------
extern "C" void kernel_launch(void* const* d_in, const int* in_sizes, int n_in,
                              void* d_out, int out_size, void* d_ws, size_t ws_size,
                              hipStream_t stream)
{
    (void)in_sizes; (void)n_in; (void)out_size; (void)ws_size;

    const float* x      = (const float*)d_in[0];
    const float* coords = (const float*)d_in[1];
    const float* Wq = (const float*)d_in[2];  const float* bq = (const float*)d_in[3];
    const float* Wk = (const float*)d_in[4];  const float* bk = (const float*)d_in[5];
    const float* Wv = (const float*)d_in[6];  const float* bv = (const float*)d_in[7];
    const float* Wo = (const float*)d_in[8];  const float* bo = (const float*)d_in[9];
    const float* Wd1 = (const float*)d_in[10]; const float* bd1 = (const float*)d_in[11];
    const float* Wd2 = (const float*)d_in[12]; const float* bd2 = (const float*)d_in[13];

    float* out_main = (float*)d_out;            // [B,N,C]
    float* attn     = out_main + QKV_ELEMS;     // [B,H,N,N]

    uint8_t* wsb = (uint8_t*)d_ws;
    const size_t SZ_BF = (size_t)BHc * Nc * Dc * 2;          // 6,291,456 B
    const size_t SZ_W4 = (size_t)4 * 768 * 768 * 2;          // 4,718,592 B
    unsigned short* qhi  = (unsigned short*)(wsb + 0 * SZ_BF);
    unsigned short* qlo  = (unsigned short*)(wsb + 1 * SZ_BF);
    unsigned short* khi  = (unsigned short*)(wsb + 2 * SZ_BF);
    unsigned short* klo  = (unsigned short*)(wsb + 3 * SZ_BF);
    unsigned short* vThi = (unsigned short*)(wsb + 4 * SZ_BF);
    unsigned short* vTlo = (unsigned short*)(wsb + 5 * SZ_BF);
    unsigned short* xhi  = (unsigned short*)(wsb + 6 * SZ_BF); // reused as Hphi
    unsigned short* xlo  = (unsigned short*)(wsb + 7 * SZ_BF); // reused as Hplo
    unsigned short* Thi  = (unsigned short*)(wsb + 8 * SZ_BF);
    unsigned short* Tlo  = (unsigned short*)(wsb + 8 * SZ_BF + SZ_W4);
    float* mlbuf  = (float*)(wsb + 8 * SZ_BF + 2 * SZ_W4);   // [BH*N][16][2]
    float* abPack = mlbuf + (size_t)BHc * Nc * 32;           // 17*12*2 floats
    unsigned char* lut = (unsigned char*)(abPack + 17 * 12 * 2); // 2048 B

    prep_w_kernel<<<dim3(12, 12, 4), 256, 0, stream>>>(Wq, Wk, Wv, Wo, Thi, Tlo);
    prep_tables_kernel<<<1, 256, 0, stream>>>(Wd1, bd1, Wd2, bd2, abPack, lut);
    split_x_kernel<<<dim3(1536), 256, 0, stream>>>(x, xhi, xlo);

    dim3 gGemm(12, 64);
    gemm_mfma_kernel<0><<<gGemm, 256, 0, stream>>>(
        xhi, xlo, Thi + (size_t)0 * 768 * 768, Tlo + (size_t)0 * 768 * 768,
        bq, nullptr, qhi, qlo);
    gemm_mfma_kernel<0><<<gGemm, 256, 0, stream>>>(
        xhi, xlo, Thi + (size_t)1 * 768 * 768, Tlo + (size_t)1 * 768 * 768,
        bk, nullptr, khi, klo);
    gemm_mfma_kernel<1><<<gGemm, 256, 0, stream>>>(
        xhi, xlo, Thi + (size_t)2 * 768 * 768, Tlo + (size_t)2 * 768 * 768,
        bv, nullptr, vThi, vTlo);

    scores_kernel<<<dim3(16, 2, 48), 256, 0, stream>>>(
        qhi, qlo, khi, klo, coords, abPack, lut, attn, mlbuf);

    pv_kernel<<<dim3(32, 48), 256, 0, stream>>>(
        attn, vThi, vTlo, mlbuf, xhi, xlo);

    gemm_mfma_kernel<2><<<gGemm, 256, 0, stream>>>(
        xhi, xlo, Thi + (size_t)3 * 768 * 768, Tlo + (size_t)3 * 768 * 768,
        bo, out_main, nullptr, nullptr);
}

// Round 6
// 389.207 us; speedup vs baseline: 1.1649x; 1.1649x over previous
//
#include <hip/hip_runtime.h>
#include <cstddef>
#include <cstdint>

#define Bc 4
#define Nc 1024
#define Cc 768
#define Hc 12
#define Dc 64
#define BHc 48
#define QKV_ELEMS ((size_t)Bc * Nc * Cc)   // 3145728

typedef __attribute__((ext_vector_type(4))) unsigned int u32x4;
typedef __attribute__((ext_vector_type(8))) short s16x8;
typedef __attribute__((ext_vector_type(8))) _Float16 h16x8;
typedef __attribute__((ext_vector_type(4))) unsigned short u16x4;
typedef __attribute__((ext_vector_type(4))) float fx4;
typedef __attribute__((ext_vector_type(2))) float fx2;

union Frag { u32x4 u; s16x8 s; h16x8 f16; unsigned short h[8]; };
union Half4 { u16x4 q; _Float16 h[4]; };

__device__ inline unsigned short f2bf(float x) {
    union { float f; uint32_t u; } c; c.f = x;
    return (unsigned short)((c.u + 0x7FFFu + ((c.u >> 16) & 1u)) >> 16);
}
__device__ inline float bf2f(unsigned short b) {
    union { uint32_t u; float f; } c; c.u = ((uint32_t)b) << 16;
    return c.f;
}
__device__ inline void split8(const float* v, u32x4& hi, u32x4& lo) {
    Frag fh, fl;
    #pragma unroll
    for (int e = 0; e < 8; ++e) {
        const unsigned short hb = f2bf(v[e]);
        fh.h[e] = hb;
        fl.h[e] = f2bf(v[e] - bf2f(hb));
    }
    hi = fh.u; lo = fl.u;
}
__device__ inline void split8h(const float* v, u32x4& hi, u32x4& lo) {
    Frag fh, fl;
    #pragma unroll
    for (int e = 0; e < 8; ++e) {
        const _Float16 hb = (_Float16)v[e];
        fh.f16[e] = hb;
        fl.f16[e] = (_Float16)(v[e] - (float)hb);
    }
    hi = fh.u; lo = fl.u;
}

// ---------------------------------------------------------------------------
// prep_w: Wt_hi/lo[mat][n][k] = split(W[k][n])  (bf16 hi/lo)
// ---------------------------------------------------------------------------
__global__ __launch_bounds__(256) void prep_w_kernel(
    const float* __restrict__ Wq, const float* __restrict__ Wk,
    const float* __restrict__ Wv, const float* __restrict__ Wo,
    unsigned short* __restrict__ Thi, unsigned short* __restrict__ Tlo)
{
    __shared__ float scr[64 * 65];
    const int mat = blockIdx.z;
    const float* W = (mat == 0) ? Wq : (mat == 1) ? Wk : (mat == 2) ? Wv : Wo;
    const int k0 = blockIdx.y * 64, n0 = blockIdx.x * 64;
    const int tid = threadIdx.x;

    #pragma unroll
    for (int it = 0; it < 4; ++it) {
        const int lin = tid + it * 256;
        const int r = lin >> 4, c4 = (lin & 15) << 2;
        const fx4 v = *(const fx4*)&W[(size_t)(k0 + r) * 768 + n0 + c4];
        scr[r * 65 + c4 + 0] = v[0]; scr[r * 65 + c4 + 1] = v[1];
        scr[r * 65 + c4 + 2] = v[2]; scr[r * 65 + c4 + 3] = v[3];
    }
    __syncthreads();
    unsigned short* th = Thi + (size_t)mat * 768 * 768;
    unsigned short* tl = Tlo + (size_t)mat * 768 * 768;
    #pragma unroll
    for (int it = 0; it < 16; ++it) {
        const int lin = tid + it * 256;
        const int n = lin >> 6, kq = lin & 63;
        const float val = scr[kq * 65 + n];
        const size_t o = (size_t)(n0 + n) * 768 + k0 + kq;
        const unsigned short hb = f2bf(val);
        th[o] = hb;
        tl[o] = f2bf(val - bf2f(hb));
    }
}

// ---------------------------------------------------------------------------
// prep_tables: PL (alpha,beta) per (segment, h) + 2048-bin u8 idx LUT.
// ---------------------------------------------------------------------------
__global__ __launch_bounds__(256) void prep_tables_kernel(
    const float* __restrict__ Wd1, const float* __restrict__ bd1,
    const float* __restrict__ Wd2, const float* __restrict__ bd2,
    float* __restrict__ abPack, unsigned char* __restrict__ lut)
{
    __shared__ float w1s[16], b1s[16], kn[16];
    __shared__ int rank[16];
    const int tid = threadIdx.x;
    if (tid < 16) {
        const float w1 = Wd1[tid], b1 = bd1[tid];
        w1s[tid] = w1; b1s[tid] = b1;
        kn[tid] = (w1 != 0.0f) ? (-b1 / w1) : INFINITY;
    }
    __syncthreads();
    if (tid < 16) {
        int rk = 0;
        for (int u = 0; u < 16; ++u) {
            const float ku = kn[u], km = kn[tid];
            if (ku < km || (ku == km && u < tid)) ++rk;
        }
        rank[tid] = rk;
    }
    __syncthreads();
    if (tid < 17 * 12) {
        const int s = tid / 12, h = tid % 12;
        float a = 0.0f, be = bd2[h];
        for (int u = 0; u < 16; ++u) {
            const float w1 = w1s[u], b1 = b1s[u];
            bool act;
            if (w1 > 0.0f)      act = (rank[u] < s);
            else if (w1 < 0.0f) act = (rank[u] >= s);
            else                act = (b1 > 0.0f);
            if (act) {
                const float w2 = Wd2[u * 12 + h];
                a  += w2 * w1;
                be += w2 * b1;
            }
        }
        abPack[tid * 2 + 0] = a;
        abPack[tid * 2 + 1] = be;
    }
    for (int b = tid; b < 2048; b += 256) {
        const float rep = (b + 0.5f) * (1.41422f / 2048.0f);
        int cnt = 0;
        for (int t = 0; t < 16; ++t) cnt += (rep > kn[t]) ? 1 : 0;
        lut[b] = (unsigned char)cnt;
    }
}

// ---------------------------------------------------------------------------
// split_x: x fp32 -> xhi/xlo bf16 row-major
// ---------------------------------------------------------------------------
__global__ __launch_bounds__(256) void split_x_kernel(
    const float* __restrict__ x, unsigned short* __restrict__ xhi,
    unsigned short* __restrict__ xlo)
{
    const size_t t = (size_t)blockIdx.x * 256 + threadIdx.x;
    float vv[8];
    const fx4 a = *(const fx4*)&x[t * 8];
    const fx4 b = *(const fx4*)&x[t * 8 + 4];
    vv[0]=a[0]; vv[1]=a[1]; vv[2]=a[2]; vv[3]=a[3];
    vv[4]=b[0]; vv[5]=b[1]; vv[6]=b[2]; vv[7]=b[3];
    u32x4 hi, lo; split8(vv, hi, lo);
    *(u32x4*)&xhi[t * 8] = hi;
    *(u32x4*)&xlo[t * 8] = lo;
}

// ---------------------------------------------------------------------------
// gemm_mfma: out = A[4096x768] @ W[768x768] + bias, bf16x3 MFMA.
// OMODE 0: bf16 hi/lo head layout [bh][n][d] (q,k)
// OMODE 1: f16 hi/lo vT [bh][d][n] (v)
// OMODE 2: fp32 row-major (final out)
// ---------------------------------------------------------------------------
struct SmemG { u32x4 ah[512]; u32x4 al[512]; u32x4 bh[512]; u32x4 bl[512]; };
struct SmemT { float scr[64 * 68]; };
union SmemU { SmemG g; SmemT t; };

template<int OMODE>
__global__ __launch_bounds__(256) void gemm_mfma_kernel(
    const unsigned short* __restrict__ Ahi, const unsigned short* __restrict__ Alo,
    const unsigned short* __restrict__ Bhi, const unsigned short* __restrict__ Blo,
    const float* __restrict__ bias,
    float* __restrict__ outF,
    unsigned short* __restrict__ Ohi, unsigned short* __restrict__ Olo)
{
    __shared__ SmemU sm;
    const int tid = threadIdx.x;
    const int w = tid >> 6, L = tid & 63;
    const int Lr = L & 15, Lg = L >> 4;
    const int m0 = blockIdx.y * 64, n0 = blockIdx.x * 64;

    fx4 acc[2][2] = {};

    for (int kk = 0; kk < 768; kk += 64) {
        #pragma unroll
        for (int it = 0; it < 2; ++it) {
            const int slot = tid + it * 256;
            const int s = slot >> 6, l = slot & 63;
            const int row = m0 + ((s >> 1) << 4) + (l & 15);
            const int kb = kk + ((s & 1) << 5) + ((l >> 4) << 3);
            sm.g.ah[slot] = *(const u32x4*)&Ahi[(size_t)row * 768 + kb];
            sm.g.al[slot] = *(const u32x4*)&Alo[(size_t)row * 768 + kb];
            const int col = n0 + ((s >> 1) << 4) + (l & 15);
            sm.g.bh[slot] = *(const u32x4*)&Bhi[(size_t)col * 768 + kb];
            sm.g.bl[slot] = *(const u32x4*)&Blo[(size_t)col * 768 + kb];
        }
        __syncthreads();
        #pragma unroll
        for (int kc = 0; kc < 2; ++kc) {
            Frag ah[2], al[2], bh[2], bl[2];
            #pragma unroll
            for (int mm = 0; mm < 2; ++mm) {
                const int rg = (w >> 1) * 2 + mm;
                ah[mm].u = sm.g.ah[(rg * 2 + kc) * 64 + L];
                al[mm].u = sm.g.al[(rg * 2 + kc) * 64 + L];
            }
            #pragma unroll
            for (int nn = 0; nn < 2; ++nn) {
                const int cg = (w & 1) * 2 + nn;
                bh[nn].u = sm.g.bh[(cg * 2 + kc) * 64 + L];
                bl[nn].u = sm.g.bl[(cg * 2 + kc) * 64 + L];
            }
            #pragma unroll
            for (int mm = 0; mm < 2; ++mm)
                #pragma unroll
                for (int nn = 0; nn < 2; ++nn) {
                    acc[mm][nn] = __builtin_amdgcn_mfma_f32_16x16x32_bf16(ah[mm].s, bh[nn].s, acc[mm][nn], 0, 0, 0);
                    acc[mm][nn] = __builtin_amdgcn_mfma_f32_16x16x32_bf16(ah[mm].s, bl[nn].s, acc[mm][nn], 0, 0, 0);
                    acc[mm][nn] = __builtin_amdgcn_mfma_f32_16x16x32_bf16(al[mm].s, bh[nn].s, acc[mm][nn], 0, 0, 0);
                }
        }
        __syncthreads();
    }

    #pragma unroll
    for (int mm = 0; mm < 2; ++mm) {
        const int rl = (w >> 1) * 32 + mm * 16 + Lg * 4;
        #pragma unroll
        for (int nn = 0; nn < 2; ++nn) {
            const int cl = (w & 1) * 32 + nn * 16 + Lr;
            const float bs = bias[n0 + cl];
            #pragma unroll
            for (int r = 0; r < 4; ++r)
                sm.t.scr[(rl + r) * 68 + cl] = acc[mm][nn][r] + bs;
        }
    }
    __syncthreads();

    if (OMODE == 0) {
        const int h = n0 >> 6;
        #pragma unroll
        for (int it = 0; it < 2; ++it) {
            const int t = tid + it * 256;
            const int r = t >> 3, d0 = (t & 7) << 3;
            float vv[8];
            #pragma unroll
            for (int e = 0; e < 8; ++e) vv[e] = sm.t.scr[r * 68 + d0 + e];
            u32x4 hi, lo; split8(vv, hi, lo);
            const int rg = m0 + r, b = rg >> 10, nloc = rg & 1023;
            const size_t o = (((size_t)(b * Hc + h) * Nc + nloc) << 6) + d0;
            *(u32x4*)&Ohi[o] = hi;
            *(u32x4*)&Olo[o] = lo;
        }
    } else if (OMODE == 1) {
        const int b = m0 >> 10, h = n0 >> 6, nbase = m0 & 1023;
        #pragma unroll
        for (int it = 0; it < 2; ++it) {
            const int t = tid + it * 256;
            const int dd = t >> 3, j0 = (t & 7) << 3;
            float vv[8];
            #pragma unroll
            for (int e = 0; e < 8; ++e) vv[e] = sm.t.scr[(j0 + e) * 68 + dd];
            u32x4 hi, lo; split8h(vv, hi, lo);   // f16 hi/lo for PV
            const size_t o = (size_t)((b * Hc + h) * Dc + dd) * Nc + nbase + j0;
            *(u32x4*)&Ohi[o] = hi;
            *(u32x4*)&Olo[o] = lo;
        }
    } else {
        #pragma unroll
        for (int it = 0; it < 4; ++it) {
            const int lin = tid + it * 256;
            const int r = lin >> 4, c4 = (lin & 15) << 2;
            const fx4 v = *(const fx4*)&sm.t.scr[r * 68 + c4];
            *(fx4*)&outF[(size_t)(m0 + r) * 768 + n0 + c4] = v;
        }
    }
}

// ---------------------------------------------------------------------------
// scores: per (i-tile 64, j-half, bh). K frags direct from global (L2-hot).
// Writes e = exp(s - m_tile) as f16 into e_ws (pv A-frag order);
// (m_tile, l_tile) per (row, jtg) -> mlf. No attn writes.
// ---------------------------------------------------------------------------
__global__ __launch_bounds__(256) void scores_kernel(
    const unsigned short* __restrict__ qhi, const unsigned short* __restrict__ qlo,
    const unsigned short* __restrict__ khi, const unsigned short* __restrict__ klo,
    const float* __restrict__ coords,
    const float* __restrict__ abPack, const unsigned char* __restrict__ lutg,
    unsigned short* __restrict__ e_ws, float* __restrict__ mlf)
{
    __shared__ fx2 abt[17];
    __shared__ unsigned char luts[2048];
    __shared__ fx2 cjs[512];

    const int tid = threadIdx.x;
    const int w = tid >> 6, L = tid & 63;
    const int Lr = L & 15, Lg = L >> 4;
    const int bh = blockIdx.z, b = bh / Hc, h = bh % Hc;
    const int i0 = blockIdx.x * 64, half = blockIdx.y;
    const int i = i0 + w * 16 + Lr;
    const int Lg4 = Lg * 4;

    if (tid < 17) abt[tid] = ((const fx2*)abPack)[tid * Hc + h];
    for (int t = tid; t < 512; t += 256) {
        ((uint32_t*)luts)[t] = ((const uint32_t*)lutg)[t];
        cjs[t] = *(const fx2*)&coords[((size_t)b * Nc + half * 512 + t) * 2];
    }

    Frag qh[2], ql[2];
    #pragma unroll
    for (int kc = 0; kc < 2; ++kc) {
        const size_t o = ((size_t)bh * Nc + i) * 64 + kc * 32 + Lg * 8;
        qh[kc].u = *(const u32x4*)&qhi[o];
        ql[kc].u = *(const u32x4*)&qlo[o];
    }
    const fx2 ci = *(const fx2*)&coords[((size_t)b * Nc + i) * 2];
    __syncthreads();

    const size_t mlbase = ((size_t)bh * Nc + i) * 16 + half * 8;

    for (int jt = 0; jt < 8; ++jt) {
        const int jbase = half * 512 + jt * 64;
        const int jtg = half * 8 + jt;

        fx4 acc[4] = {};
        #pragma unroll
        for (int kc = 0; kc < 2; ++kc) {
            Frag kh[4], kl[4];
            #pragma unroll
            for (int cg = 0; cg < 4; ++cg) {
                const size_t o = ((size_t)bh * Nc + jbase + cg * 16 + Lr) * 64 + kc * 32 + Lg * 8;
                kh[cg].u = *(const u32x4*)&khi[o];
                kl[cg].u = *(const u32x4*)&klo[o];
            }
            #pragma unroll
            for (int cg = 0; cg < 4; ++cg) {
                acc[cg] = __builtin_amdgcn_mfma_f32_16x16x32_bf16(kh[cg].s, qh[kc].s, acc[cg], 0, 0, 0);
                acc[cg] = __builtin_amdgcn_mfma_f32_16x16x32_bf16(kl[cg].s, qh[kc].s, acc[cg], 0, 0, 0);
                acc[cg] = __builtin_amdgcn_mfma_f32_16x16x32_bf16(kh[cg].s, ql[kc].s, acc[cg], 0, 0, 0);
            }
        }

        float sv[16];
        #pragma unroll
        for (int cg = 0; cg < 4; ++cg) {
            #pragma unroll
            for (int r = 0; r < 4; ++r) {
                const fx2 cj = cjs[jt * 64 + cg * 16 + Lg4 + r + (half * 512 == jbase - jt * 64 ? 0 : 0)];
                const float dx = ci[0] - cj[0], dy = ci[1] - cj[1];
                const float dist = sqrtf(fmaf(dx, dx, fmaf(dy, dy, 1e-6f)));
                int bin = (int)(dist * (2048.0f / 1.41422f));
                bin = (bin > 2047) ? 2047 : bin;
                const fx2 ab = abt[luts[bin]];
                sv[cg * 4 + r] = fmaf(acc[cg][r], 0.125f, fmaf(ab[0], dist, ab[1]));
            }
        }

        float tm = sv[0];
        #pragma unroll
        for (int e = 1; e < 16; ++e) tm = fmaxf(tm, sv[e]);
        tm = fmaxf(tm, __shfl_xor(tm, 16));
        tm = fmaxf(tm, __shfl_xor(tm, 32));

        float ts = 0.f;
        #pragma unroll
        for (int e = 0; e < 16; ++e) { sv[e] = __expf(sv[e] - tm); ts += sv[e]; }

        // store e as f16 in pv A-frag order:
        // value j' = cg*16 + Lg*4 + r  ->  idx = kc*32768 + i*32 + Lgp*8 + (Lg&1)*4 + r
        const size_t eT = (((size_t)bh * 16 + jtg) << 16);
        #pragma unroll
        for (int cg = 0; cg < 4; ++cg) {
            Half4 hs;
            #pragma unroll
            for (int r = 0; r < 4; ++r) hs.h[r] = (_Float16)sv[cg * 4 + r];
            const int kc = cg >> 1;
            const int Lgp = (cg & 1) * 2 + (Lg >> 1);
            const size_t eoff = eT + (size_t)kc * 32768 + (size_t)i * 32 + Lgp * 8 + (Lg & 1) * 4;
            *(u16x4*)&e_ws[eoff] = hs.q;
        }

        ts += __shfl_xor(ts, 16);
        ts += __shfl_xor(ts, 32);
        if (Lg == 0) {
            *(fx2*)&mlf[(mlbase + jt) * 2] = fx2{tm, ts};
        }
    }
}

// ---------------------------------------------------------------------------
// pv: p = e * f (f per (row, jt)); write p (f32) to attn ONCE; PV via f16 MFMA
// with V staged in LDS frag-order. Block: 64 rows, 4 waves, full j.
// ---------------------------------------------------------------------------
union PvSmem {
    struct { u32x4 vh[512]; u32x4 vl[512]; } v;
    float scr[64 * 68];
};

__global__ __launch_bounds__(256) void pv_kernel(
    const unsigned short* __restrict__ e_ws,
    const unsigned short* __restrict__ vThi, const unsigned short* __restrict__ vTlo,
    const float* __restrict__ mlf,
    float* __restrict__ attn,
    unsigned short* __restrict__ Hphi, unsigned short* __restrict__ Hplo)
{
    __shared__ PvSmem sm;
    const int tid = threadIdx.x;
    const int w = tid >> 6, L = tid & 63;
    const int Lr = L & 15, Lg = L >> 4;
    const int bh = blockIdx.y, b = bh / Hc, h = bh % Hc;
    const int i0 = blockIdx.x * 64;
    const int i = i0 + w * 16 + Lr;

    // row stats from per-tile (m,l)
    const float* mlr = &mlf[((size_t)bh * Nc + i) * 32];
    float mt[16], lt[16];
    #pragma unroll
    for (int t = 0; t < 8; ++t) {
        const fx4 v = *(const fx4*)&mlr[t * 4];
        mt[t*2+0] = v[0]; lt[t*2+0] = v[1];
        mt[t*2+1] = v[2]; lt[t*2+1] = v[3];
    }
    float m_row = mt[0];
    #pragma unroll
    for (int t = 1; t < 16; ++t) m_row = fmaxf(m_row, mt[t]);
    float l_row = 0.f;
    #pragma unroll
    for (int t = 0; t < 16; ++t) l_row = fmaf(lt[t], __expf(mt[t] - m_row), l_row);
    const float il = 1.0f / l_row;

    fx4 acc[4] = {};
    const size_t arow = ((size_t)bh * Nc + i) * Nc;

    #pragma unroll
    for (int jt = 0; jt < 16; ++jt) {
        const int jbase = jt * 64;
        // stage V tile (frag-order: slot (dg*2+kc)*64 + L)
        #pragma unroll
        for (int it = 0; it < 2; ++it) {
            const int s = tid + it * 256;
            const int l = s & 63;
            const int dd = ((s >> 7) << 4) + (l & 15);
            const int jo = jbase + ((s >> 6) & 1) * 32 + ((l >> 4) << 3);
            const size_t off = ((size_t)bh * Dc + dd) * Nc + jo;
            sm.v.vh[s] = *(const u32x4*)&vThi[off];
            sm.v.vl[s] = *(const u32x4*)&vTlo[off];
        }
        __syncthreads();

        const float f = __expf(mt[jt] - m_row) * il;
        const _Float16 fh = (_Float16)f;
        const size_t eT = (((size_t)bh * 16 + jt) << 16) + (size_t)i * 32 + Lg * 8;

        #pragma unroll
        for (int kc = 0; kc < 2; ++kc) {
            Frag ef;
            ef.u = *(const u32x4*)&e_ws[eT + kc * 32768];
            // f32 p -> attn (write-once)
            float pf[8];
            #pragma unroll
            for (int e = 0; e < 8; ++e) pf[e] = (float)ef.f16[e] * f;
            fx4 w0, w1;
            w0[0]=pf[0]; w0[1]=pf[1]; w0[2]=pf[2]; w0[3]=pf[3];
            w1[0]=pf[4]; w1[1]=pf[5]; w1[2]=pf[6]; w1[3]=pf[7];
            float* ap = &attn[arow + jbase + kc * 32 + Lg * 8];
            *(fx4*)ap = w0;
            *(fx4*)(ap + 4) = w1;
            // f16 A-fragment
            Frag pa;
            pa.f16 = ef.f16 * fh;
            #pragma unroll
            for (int dg = 0; dg < 4; ++dg) {
                Frag vh, vl;
                vh.u = sm.v.vh[(dg * 2 + kc) * 64 + L];
                vl.u = sm.v.vl[(dg * 2 + kc) * 64 + L];
                acc[dg] = __builtin_amdgcn_mfma_f32_16x16x32_f16(pa.f16, vh.f16, acc[dg], 0, 0, 0);
                acc[dg] = __builtin_amdgcn_mfma_f32_16x16x32_f16(pa.f16, vl.f16, acc[dg], 0, 0, 0);
            }
        }
        __syncthreads();
    }

    // epilogue: stage acc to LDS, vectorized bf16 hi/lo heads store
    #pragma unroll
    for (int dg = 0; dg < 4; ++dg)
        #pragma unroll
        for (int r = 0; r < 4; ++r)
            sm.scr[(w * 16 + Lg * 4 + r) * 68 + dg * 16 + Lr] = acc[dg][r];
    __syncthreads();

    #pragma unroll
    for (int it = 0; it < 2; ++it) {
        const int lin = tid + it * 256;
        const int row = lin >> 3, d0 = (lin & 7) << 3;
        float vv[8];
        #pragma unroll
        for (int e = 0; e < 8; ++e) vv[e] = sm.scr[row * 68 + d0 + e];
        u32x4 hi, lo; split8(vv, hi, lo);
        const size_t o = ((size_t)b * Nc + i0 + row) * Cc + h * Dc + d0;
        *(u32x4*)&Hphi[o] = hi;
        *(u32x4*)&Hplo[o] = lo;
    }
}

// ---------------------------------------------------------------------------
extern "C" void kernel_launch(void* const* d_in, const int* in_sizes, int n_in,
                              void* d_out, int out_size, void* d_ws, size_t ws_size,
                              hipStream_t stream)
{
    (void)in_sizes; (void)n_in; (void)out_size; (void)ws_size;

    const float* x      = (const float*)d_in[0];
    const float* coords = (const float*)d_in[1];
    const float* Wq = (const float*)d_in[2];  const float* bq = (const float*)d_in[3];
    const float* Wk = (const float*)d_in[4];  const float* bk = (const float*)d_in[5];
    const float* Wv = (const float*)d_in[6];  const float* bv = (const float*)d_in[7];
    const float* Wo = (const float*)d_in[8];  const float* bo = (const float*)d_in[9];
    const float* Wd1 = (const float*)d_in[10]; const float* bd1 = (const float*)d_in[11];
    const float* Wd2 = (const float*)d_in[12]; const float* bd2 = (const float*)d_in[13];

    float* out_main = (float*)d_out;            // [B,N,C]
    float* attn     = out_main + QKV_ELEMS;     // [B,H,N,N]

    uint8_t* wsb = (uint8_t*)d_ws;
    const size_t SZ_BF = (size_t)BHc * Nc * Dc * 2;          // 6,291,456 B
    const size_t SZ_W4 = (size_t)4 * 768 * 768 * 2;          // 4,718,592 B
    unsigned short* qhi  = (unsigned short*)(wsb + 0 * SZ_BF);
    unsigned short* qlo  = (unsigned short*)(wsb + 1 * SZ_BF);
    unsigned short* khi  = (unsigned short*)(wsb + 2 * SZ_BF);
    unsigned short* klo  = (unsigned short*)(wsb + 3 * SZ_BF);
    unsigned short* vThi = (unsigned short*)(wsb + 4 * SZ_BF);
    unsigned short* vTlo = (unsigned short*)(wsb + 5 * SZ_BF);
    unsigned short* xhi  = (unsigned short*)(wsb + 6 * SZ_BF); // reused as Hphi
    unsigned short* xlo  = (unsigned short*)(wsb + 7 * SZ_BF); // reused as Hplo
    unsigned short* Thi  = (unsigned short*)(wsb + 8 * SZ_BF);
    unsigned short* Tlo  = (unsigned short*)(wsb + 8 * SZ_BF + SZ_W4);
    float* mlbuf  = (float*)(wsb + 8 * SZ_BF + 2 * SZ_W4);   // [BH*N][16][2]
    float* abPack = mlbuf + (size_t)BHc * Nc * 32;           // 17*12*2 floats
    unsigned char* lut = (unsigned char*)(abPack + 17 * 12 * 2); // 2048 B
    unsigned short* e_ws = (unsigned short*)(wsb + 8 * SZ_BF + 2 * SZ_W4
                              + (size_t)BHc * Nc * 32 * 4 + 8192);  // f16 e, 100.7 MB

    prep_w_kernel<<<dim3(12, 12, 4), 256, 0, stream>>>(Wq, Wk, Wv, Wo, Thi, Tlo);
    prep_tables_kernel<<<1, 256, 0, stream>>>(Wd1, bd1, Wd2, bd2, abPack, lut);
    split_x_kernel<<<dim3(1536), 256, 0, stream>>>(x, xhi, xlo);

    dim3 gGemm(12, 64);
    gemm_mfma_kernel<0><<<gGemm, 256, 0, stream>>>(
        xhi, xlo, Thi + (size_t)0 * 768 * 768, Tlo + (size_t)0 * 768 * 768,
        bq, nullptr, qhi, qlo);
    gemm_mfma_kernel<0><<<gGemm, 256, 0, stream>>>(
        xhi, xlo, Thi + (size_t)1 * 768 * 768, Tlo + (size_t)1 * 768 * 768,
        bk, nullptr, khi, klo);
    gemm_mfma_kernel<1><<<gGemm, 256, 0, stream>>>(
        xhi, xlo, Thi + (size_t)2 * 768 * 768, Tlo + (size_t)2 * 768 * 768,
        bv, nullptr, vThi, vTlo);

    scores_kernel<<<dim3(16, 2, 48), 256, 0, stream>>>(
        qhi, qlo, khi, klo, coords, abPack, lut, e_ws, mlbuf);

    pv_kernel<<<dim3(16, 48), 256, 0, stream>>>(
        e_ws, vThi, vTlo, mlbuf, attn, xhi, xlo);

    gemm_mfma_kernel<2><<<gGemm, 256, 0, stream>>>(
        xhi, xlo, Thi + (size_t)3 * 768 * 768, Tlo + (size_t)3 * 768 * 768,
        bo, out_main, nullptr, nullptr);
}